// Round 7
// baseline (360.589 us; speedup 1.0000x reference)
//
#include <hip/hip_runtime.h>

#define M_NODES 100
#define HDIM 512
#define MH (M_NODES*HDIM)       // 51200
#define WNE_IT (1540*512)

typedef __attribute__((ext_vector_type(8))) short short8v;   // 8 bf16 (4 VGPRs)
typedef __attribute__((ext_vector_type(4))) float float4v;   // MFMA acc

static __device__ __forceinline__ short f2b(float f) {
    union { float f; unsigned u; } v; v.f = f;
    unsigned r = (v.u + 0x7FFF + ((v.u >> 16) & 1)) >> 16;   // RNE
    return (short)r;
}

// ---- front: w3prep (0..511) + child split-K partials (512..911)
//      + zero child1/child2 (912..1011) + zero flag/jcount (block 0) ----
__global__ void front_kernel(const float* __restrict__ W_ne, short* __restrict__ W3t,
                             const float* __restrict__ parent, const float* __restrict__ Wp,
                             float* __restrict__ partial_c, int* __restrict__ flagjc,
                             float* __restrict__ child12) {
    __shared__ float sh[32 * 33];
    int bx = blockIdx.x, t = threadIdx.x;
    if (bx == 0 && t < 101) flagjc[t] = 0;          // flag + jcount[100]
    if (bx < 512) {
        int it = bx >> 8, rem = bx & 255, kt = rem & 15, ht = rem >> 4;
        const float* W3 = W_ne + (size_t)it * WNE_IT + 1024 * 512;
        int tx = t & 31, ty = t >> 5;               // ty 0..7
        #pragma unroll
        for (int r = 0; r < 4; ++r) {
            int k = kt * 32 + ty * 4 + r;
            sh[(ty * 4 + r) * 33 + tx] = W3[(size_t)k * 512 + ht * 32 + tx];
        }
        __syncthreads();
        #pragma unroll
        for (int r = 0; r < 4; ++r) {
            int h = ht * 32 + ty * 4 + r;
            W3t[(size_t)it * 262144 + (size_t)h * 512 + kt * 32 + tx] = f2b(sh[tx * 33 + ty * 4 + r]);
        }
    } else if (bx < 912) {
        int b = bx - 512;
        int bxx = b % 50, byy = b / 50;
        float* p = sh;                               // 64 floats
        int kc = byy * 64;
        if (t < 64) p[t] = parent[kc + t];
        __syncthreads();
        int o4 = (bxx * 256 + t) * 4;
        float4 acc = make_float4(0.f, 0.f, 0.f, 0.f);
        #pragma unroll 4
        for (int k = 0; k < 64; ++k) {
            float4 w = *(const float4*)(Wp + (size_t)(kc + k) * MH + o4);
            float pv = p[k];
            acc.x += pv * w.x; acc.y += pv * w.y; acc.z += pv * w.z; acc.w += pv * w.w;
        }
        *(float4*)(partial_c + (size_t)byy * MH + o4) = acc;
    } else {
        int id = (bx - 912) * 256 + t;               // 25600 float4 = 2*MH floats
        *(float4*)(child12 + (size_t)id * 4) = make_float4(0.f, 0.f, 0.f, 0.f);
    }
}

// tree-reduce helper over the 16 K-chunks: red[4][256], index = kq*16+g
static __device__ __forceinline__ void ks16_tree(float4 (*red)[256], int t) {
    #pragma unroll
    for (int st = 128; st >= 16; st >>= 1) {
        if (t < st) {
            #pragma unroll
            for (int r = 0; r < 4; ++r) {
                float4 a = red[r][t], b = red[r][t + st];
                a.x += b.x; a.y += b.y; a.z += b.z; a.w += b.w;
                red[r][t] = a;
            }
        }
        __syncthreads();
    }
}

// ---- quad GEMM, K-split-16 in block: grid (32,25). Fused child-fold + exists. ----
__global__ __launch_bounds__(256) void
quad_ex(const float* __restrict__ partial_c, const float* __restrict__ bp,
        const float* __restrict__ Wex, const float* __restrict__ bex,
        const float* __restrict__ B0, const float* __restrict__ B1,
        const float* __restrict__ B2, const float* __restrict__ B3,
        const float* __restrict__ bias0, const float* __restrict__ bias2,
        float* __restrict__ child0, float* __restrict__ exists_out, int* __restrict__ node_ok,
        float* __restrict__ O0, float* __restrict__ O1,
        float* __restrict__ O2, float* __restrict__ O3) {
    __shared__ float As[4][512];
    __shared__ float4 red[4][256];
    int t = threadIdx.x, bx = blockIdx.x, m0 = blockIdx.y * 4;
    // fold 8 partials + bias + relu -> As (child0 / exists from bx==0 blocks only)
    // NOTE: b_parent is the FULL [M*H]=51200 bias — index with the flat gcol,
    // NOT gcol&511 (that aliasing was round-5's correctness bug).
    #pragma unroll
    for (int q2 = 0; q2 < 2; ++q2) {
        int slot = t + q2 * 256;
        int row = slot >> 7, c4 = (slot & 127) * 4;
        int gcol = (m0 + row) * 512 + c4;
        float4 s = *(const float4*)(bp + gcol);
        #pragma unroll
        for (int q = 0; q < 8; ++q) {
            float4 v = *(const float4*)(partial_c + (size_t)q * MH + gcol);
            s.x += v.x; s.y += v.y; s.z += v.z; s.w += v.w;
        }
        s.x = fmaxf(s.x, 0.f); s.y = fmaxf(s.y, 0.f);
        s.z = fmaxf(s.z, 0.f); s.w = fmaxf(s.w, 0.f);
        *(float4*)&As[row][c4] = s;
        if (bx == 0) *(float4*)(child0 + gcol) = s;
    }
    __syncthreads();
    if (bx == 0) {                                 // exists logits + node_ok
        int r = t >> 6, l = t & 63;
        const float* a = &As[r][l * 8];
        const float* w = Wex + l * 8;
        float s = a[0]*w[0] + a[1]*w[1] + a[2]*w[2] + a[3]*w[3]
                + a[4]*w[4] + a[5]*w[5] + a[6]*w[6] + a[7]*w[7];
        #pragma unroll
        for (int off = 32; off; off >>= 1) s += __shfl_down(s, off);
        if (l == 0) {
            float v = s + bex[0];
            exists_out[m0 + r] = v;
            node_ok[m0 + r] = (v > 0.f) ? 1 : 0;
        }
    }
    // K-split-16: thread (kq=t>>4, g=t&15); block covers 16 col4-groups
    int kq = t >> 4, g = t & 15;
    int col4 = bx * 16 + g, which = col4 >> 7, nn4 = col4 & 127;
    const float* B = (which == 0) ? B0 : (which == 1) ? B1 : (which == 2) ? B2 : B3;
    const float* bpB = B + nn4 * 4;
    float4 a0 = {0,0,0,0}, a1 = {0,0,0,0}, a2 = {0,0,0,0}, a3 = {0,0,0,0};
    int k0 = kq * 32;
    #pragma unroll 8
    for (int i = 0; i < 32; ++i) {
        int kk = k0 + i;
        float4 b = *(const float4*)(bpB + (size_t)kk * 512);
        float x0 = As[0][kk], x1 = As[1][kk], x2 = As[2][kk], x3 = As[3][kk];
        a0.x += x0*b.x; a0.y += x0*b.y; a0.z += x0*b.z; a0.w += x0*b.w;
        a1.x += x1*b.x; a1.y += x1*b.y; a1.z += x1*b.z; a1.w += x1*b.w;
        a2.x += x2*b.x; a2.y += x2*b.y; a2.z += x2*b.z; a2.w += x2*b.w;
        a3.x += x3*b.x; a3.y += x3*b.y; a3.z += x3*b.z; a3.w += x3*b.w;
    }
    red[0][t] = a0; red[1][t] = a1; red[2][t] = a2; red[3][t] = a3;
    __syncthreads();
    ks16_tree(red, t);
    if (t < 64) {
        int r2 = t >> 4, g2 = t & 15;
        int col4b = bx * 16 + g2, which2 = col4b >> 7, nn4b = col4b & 127;
        float4 s = red[r2][g2];
        if (which2 == 0) {
            float4 bb = *(const float4*)(bias0 + nn4b * 4);
            s.x += bb.x; s.y += bb.y; s.z += bb.z; s.w += bb.w;
        } else if (which2 == 2) {
            float4 bb = *(const float4*)(bias2 + nn4b * 4);
            s.x += bb.x; s.y += bb.y; s.z += bb.z; s.w += bb.w;
        }
        float* O = (which2 == 0) ? O0 : (which2 == 1) ? O1 : (which2 == 2) ? O2 : O3;
        *(float4*)(O + (size_t)(m0 + r2) * 512 + nn4b * 4) = s;
    }
}

// ---- it=1 A/B recompute, K-split-16: grid (16,25). A = flag ? child1 : child0 ----
__global__ __launch_bounds__(256) void
dual_ab(const int* __restrict__ flagp, const float* __restrict__ A0, const float* __restrict__ A1,
        const float* __restrict__ B0, const float* __restrict__ B1,
        const float* __restrict__ bias0, float* __restrict__ O0, float* __restrict__ O1) {
    __shared__ float As[4][512];
    __shared__ float4 red[4][256];
    int t = threadIdx.x, bx = blockIdx.x, m0 = blockIdx.y * 4;
    const float* A = (*flagp) ? A1 : A0;
    #pragma unroll
    for (int q2 = 0; q2 < 2; ++q2) {
        int slot = t + q2 * 256;
        int row = slot >> 7, c4 = (slot & 127) * 4;
        *(float4*)&As[row][c4] = *(const float4*)(A + (size_t)(m0 + row) * 512 + c4);
    }
    __syncthreads();
    int kq = t >> 4, g = t & 15;
    int col4 = bx * 16 + g;
    bool second = col4 >= 128;
    const float* B = second ? B1 : B0;
    int nn4 = col4 & 127;
    const float* bpB = B + nn4 * 4;
    float4 a0 = {0,0,0,0}, a1 = {0,0,0,0}, a2 = {0,0,0,0}, a3 = {0,0,0,0};
    int k0 = kq * 32;
    #pragma unroll 8
    for (int i = 0; i < 32; ++i) {
        int kk = k0 + i;
        float4 b = *(const float4*)(bpB + (size_t)kk * 512);
        float x0 = As[0][kk], x1 = As[1][kk], x2 = As[2][kk], x3 = As[3][kk];
        a0.x += x0*b.x; a0.y += x0*b.y; a0.z += x0*b.z; a0.w += x0*b.w;
        a1.x += x1*b.x; a1.y += x1*b.y; a1.z += x1*b.z; a1.w += x1*b.w;
        a2.x += x2*b.x; a2.y += x2*b.y; a2.z += x2*b.z; a2.w += x2*b.w;
        a3.x += x3*b.x; a3.y += x3*b.y; a3.z += x3*b.z; a3.w += x3*b.w;
    }
    red[0][t] = a0; red[1][t] = a1; red[2][t] = a2; red[3][t] = a3;
    __syncthreads();
    ks16_tree(red, t);
    if (t < 64) {
        int r2 = t >> 4, g2 = t & 15;
        int col4b = bx * 16 + g2;
        bool sec2 = col4b >= 128;
        int nn4b = col4b & 127;
        float4 s = red[r2][g2];
        if (!sec2) {
            float4 bb = *(const float4*)(bias0 + nn4b * 4);
            s.x += bb.x; s.y += bb.y; s.z += bb.z; s.w += bb.w;
        }
        float* O = sec2 ? O1 : O0;
        *(float4*)(O + (size_t)(m0 + r2) * 512 + nn4b * 4) = s;
    }
}

// ---- hcat GEMM [100,1536]xW_child, K-split-16: grid (8,25) ----
__global__ __launch_bounds__(256) void
perm1536(const int* __restrict__ flagp, const float* __restrict__ cb,
         const float* __restrict__ B, const float* __restrict__ bias, float* __restrict__ O) {
    __shared__ float As[4][1536];
    __shared__ float4 red[4][256];
    int t = threadIdx.x, bx = blockIdx.x, m0 = blockIdx.y * 4;
    int flag = *flagp;
    #pragma unroll
    for (int q2 = 0; q2 < 6; ++q2) {
        int slot = t + q2 * 256;                  // 1536 float4 slots: 4 rows x 384
        int row = slot / 384;
        int c4 = (slot - row * 384) * 4;
        int seg = c4 >> 9, off = c4 & 511;
        int se = flag ? seg : 0;                  // no-edge fallback: all segments = child0
        *(float4*)&As[row][c4] = *(const float4*)(cb + (size_t)se * MH + (size_t)(m0 + row) * 512 + off);
    }
    __syncthreads();
    int kq = t >> 4, g = t & 15;
    int nn4 = bx * 16 + g;                        // 0..127 (N=512)
    const float* bpB = B + nn4 * 4;
    float4 a0 = {0,0,0,0}, a1 = {0,0,0,0}, a2 = {0,0,0,0}, a3 = {0,0,0,0};
    int k0 = kq * 96;
    #pragma unroll 8
    for (int i = 0; i < 96; ++i) {
        int kk = k0 + i;
        float4 b = *(const float4*)(bpB + (size_t)kk * 512);
        float x0 = As[0][kk], x1 = As[1][kk], x2 = As[2][kk], x3 = As[3][kk];
        a0.x += x0*b.x; a0.y += x0*b.y; a0.z += x0*b.z; a0.w += x0*b.w;
        a1.x += x1*b.x; a1.y += x1*b.y; a1.z += x1*b.z; a1.w += x1*b.w;
        a2.x += x2*b.x; a2.y += x2*b.y; a2.z += x2*b.z; a2.w += x2*b.w;
        a3.x += x3*b.x; a3.y += x3*b.y; a3.z += x3*b.z; a3.w += x3*b.w;
    }
    red[0][t] = a0; red[1][t] = a1; red[2][t] = a2; red[3][t] = a3;
    __syncthreads();
    ks16_tree(red, t);
    if (t < 64) {
        int r2 = t >> 4, g2 = t & 15;
        int nn4b = bx * 16 + g2;
        float4 s = red[r2][g2];
        float4 bb = *(const float4*)(bias + nn4b * 4);
        s.x = fmaxf(s.x + bb.x, 0.f); s.y = fmaxf(s.y + bb.y, 0.f);
        s.z = fmaxf(s.z + bb.z, 0.f); s.w = fmaxf(s.w + bb.w, 0.f);
        *(float4*)(O + (size_t)(m0 + r2) * 512 + nn4b * 4) = s;
    }
}

// ---- final dual, K-split-16: grid (12,25). bx<8: W_child2 (relu); bx>=8: W_sem ragged ----
__global__ __launch_bounds__(256) void
dual_rag(const float* __restrict__ A,
         const float* __restrict__ B0, const float* __restrict__ bias0, float* __restrict__ O0,
         const float* __restrict__ B2, const float* __restrict__ bias2, float* __restrict__ O2) {
    __shared__ float As[4][512];
    __shared__ float4 red[4][256];
    int t = threadIdx.x, bx = blockIdx.x, m0 = blockIdx.y * 4;
    #pragma unroll
    for (int q2 = 0; q2 < 2; ++q2) {
        int slot = t + q2 * 256;
        int row = slot >> 7, c4 = (slot & 127) * 4;
        *(float4*)&As[row][c4] = *(const float4*)(A + (size_t)(m0 + row) * 512 + c4);
    }
    __syncthreads();
    int kq = t >> 4, g = t & 15;
    float4 a0 = {0,0,0,0}, a1 = {0,0,0,0}, a2 = {0,0,0,0}, a3 = {0,0,0,0};
    int k0 = kq * 32;
    if (bx < 8) {
        int nn4 = bx * 16 + g;
        const float* bpB = B0 + nn4 * 4;
        #pragma unroll 8
        for (int i = 0; i < 32; ++i) {
            int kk = k0 + i;
            float4 b = *(const float4*)(bpB + (size_t)kk * 512);
            float x0 = As[0][kk], x1 = As[1][kk], x2 = As[2][kk], x3 = As[3][kk];
            a0.x += x0*b.x; a0.y += x0*b.y; a0.z += x0*b.z; a0.w += x0*b.w;
            a1.x += x1*b.x; a1.y += x1*b.y; a1.z += x1*b.z; a1.w += x1*b.w;
            a2.x += x2*b.x; a2.y += x2*b.y; a2.z += x2*b.z; a2.w += x2*b.w;
            a3.x += x3*b.x; a3.y += x3*b.y; a3.z += x3*b.z; a3.w += x3*b.w;
        }
    } else {
        int col = (bx - 8) * 16 + g;              // 0..63 covers 57
        if (col < 57) {
            #pragma unroll 8
            for (int i = 0; i < 32; ++i) {
                int kk = k0 + i;
                float b = B2[(size_t)kk * 57 + col];
                a0.x += As[0][kk] * b; a1.x += As[1][kk] * b;
                a2.x += As[2][kk] * b; a3.x += As[3][kk] * b;
            }
        }
    }
    red[0][t] = a0; red[1][t] = a1; red[2][t] = a2; red[3][t] = a3;
    __syncthreads();
    ks16_tree(red, t);
    if (t < 64) {
        int r2 = t >> 4, g2 = t & 15;
        float4 s = red[r2][g2];
        if (bx < 8) {
            int nn4b = bx * 16 + g2;
            float4 bb = *(const float4*)(bias0 + nn4b * 4);
            s.x = fmaxf(s.x + bb.x, 0.f); s.y = fmaxf(s.y + bb.y, 0.f);
            s.z = fmaxf(s.z + bb.z, 0.f); s.w = fmaxf(s.w + bb.w, 0.f);
            *(float4*)(O0 + (size_t)(m0 + r2) * 512 + nn4b * 4) = s;
        } else {
            int col = (bx - 8) * 16 + g2;
            if (col < 57) O2[(size_t)(m0 + r2) * 57 + col] = s.x + bias2[col];
        }
    }
}

// elog (-> out) + compaction; one wave per (i, 4 consecutive j): Xi/W_ee loaded once.
__global__ void elog_kernel(const float* __restrict__ Xi, const float* __restrict__ Xj,
                            const float* __restrict__ Wee, const float* __restrict__ bee,
                            const int* __restrict__ node_ok,
                            float* __restrict__ elog, int* __restrict__ any_flag,
                            int* __restrict__ jcount, int* __restrict__ jlist) {
    int wid = threadIdx.x >> 6, lane = threadIdx.x & 63;
    int pair0 = (blockIdx.x * 4 + wid) * 4;          // 4 consecutive pairs, same i (100%4==0)
    int i = pair0 / M_NODES, j0 = pair0 - i * M_NODES;
    int k0 = lane * 8;
    float4 xa = *(const float4*)(Xi + (size_t)i * HDIM + k0);
    float4 xb = *(const float4*)(Xi + (size_t)i * HDIM + k0 + 4);
    float4 wa[4], wb[4];
    #pragma unroll
    for (int tt = 0; tt < 4; ++tt) {
        wa[tt] = *(const float4*)(Wee + tt * HDIM + k0);
        wb[tt] = *(const float4*)(Wee + tt * HDIM + k0 + 4);
    }
    int oki = node_ok[i];
    for (int jj = 0; jj < 4; ++jj) {
        int j = j0 + jj;
        float4 ya = *(const float4*)(Xj + (size_t)j * HDIM + k0);
        float4 yb = *(const float4*)(Xj + (size_t)j * HDIM + k0 + 4);
        float e0 = fmaxf(xa.x + ya.x, 0.f), e1 = fmaxf(xa.y + ya.y, 0.f);
        float e2 = fmaxf(xa.z + ya.z, 0.f), e3 = fmaxf(xa.w + ya.w, 0.f);
        float e4 = fmaxf(xb.x + yb.x, 0.f), e5 = fmaxf(xb.y + yb.y, 0.f);
        float e6 = fmaxf(xb.z + yb.z, 0.f), e7 = fmaxf(xb.w + yb.w, 0.f);
        float s[4];
        #pragma unroll
        for (int tt = 0; tt < 4; ++tt) {
            s[tt] = e0*wa[tt].x + e1*wa[tt].y + e2*wa[tt].z + e3*wa[tt].w
                  + e4*wb[tt].x + e5*wb[tt].y + e6*wb[tt].z + e7*wb[tt].w;
        }
        #pragma unroll
        for (int off = 32; off; off >>= 1) {
            s[0] += __shfl_down(s[0], off); s[1] += __shfl_down(s[1], off);
            s[2] += __shfl_down(s[2], off); s[3] += __shfl_down(s[3], off);
        }
        if (lane == 0) {
            int pair = pair0 + jj;
            bool ok = oki && node_ok[j];
            float lg0 = s[0] + bee[0], lg1 = s[1] + bee[1];
            float lg2 = s[2] + bee[2], lg3 = s[3] + bee[3];
            elog[pair * 4 + 0] = lg0; elog[pair * 4 + 1] = lg1;
            elog[pair * 4 + 2] = lg2; elog[pair * 4 + 3] = lg3;
            bool any = ok && (lg0 > 0.f || lg1 > 0.f || lg2 > 0.f || lg3 > 0.f);
            if (any) {
                int slot = atomicAdd(&jcount[i], 1);
                jlist[i * 112 + slot] = j;
                if (*(volatile int*)any_flag == 0) atomicOr(any_flag, 1);
            }
        }
    }
}

// ---- MFMA message step, h-split: block (jt, hs, i) covers 256 h-cols, 256 thr.
//      Halves per-block W3t bytes (256 KB), doubles live blocks. atomicAdd accumulate. ----
__global__ __launch_bounds__(256) void
msgmfma(const float* __restrict__ Xi, const float* __restrict__ Xj,
        const float* __restrict__ Abuf, const float* __restrict__ Bbuf,
        const short* __restrict__ W3t, const float* __restrict__ W4,
        const float* __restrict__ elog, const int* __restrict__ jcount,
        const int* __restrict__ jlist, float* __restrict__ child_next) {
    __shared__ short ELb[16][520];             // bf16, +8 pad
    __shared__ int jrow[16];
    int i = blockIdx.y;
    int jt = blockIdx.x >> 1, hs = blockIdx.x & 1;
    int jcnt = jcount[i];
    int j0 = jt * 16;
    if (j0 >= jcnt) return;                    // sparse early-exit (child_next pre-zeroed)
    int t = threadIdx.x;
    int wave = t >> 6, lane = t & 63;

    if (t < 16) jrow[t] = (j0 + t < jcnt) ? jlist[i * 112 + j0 + t] : -1;
    __syncthreads();
    int k0 = (t & 127) * 4;
    int r0 = t >> 7;                           // 0..1
    float4 xi = *(const float4*)(Xi + (size_t)i * HDIM + k0);
    #pragma unroll
    for (int s = 0; s < 8; ++s) {
        int row = r0 + s * 2;                  // covers 16 rows
        int j = jrow[row];
        short4 b;
        if (j >= 0) {
            float4 xj = *(const float4*)(Xj + (size_t)j * HDIM + k0);
            b.x = f2b(fmaxf(xi.x + xj.x, 0.f));
            b.y = f2b(fmaxf(xi.y + xj.y, 0.f));
            b.z = f2b(fmaxf(xi.z + xj.z, 0.f));
            b.w = f2b(fmaxf(xi.w + xj.w, 0.f));
        } else {
            b.x = b.y = b.z = b.w = 0;
        }
        *(short4*)&ELb[row][k0] = b;
    }
    __syncthreads();

    int n = lane & 15, quad = lane >> 4;
    int h0w = hs * 256 + wave * 64;            // 4 waves x 64 cols = 256-col slice
    float4v acc[4];
    #pragma unroll
    for (int nt = 0; nt < 4; ++nt) acc[nt] = (float4v){0.f, 0.f, 0.f, 0.f};

    for (int kc = 0; kc < 16; ++kc) {
        int koff = kc * 32 + quad * 8;
        short8v a = *(const short8v*)&ELb[n][koff];
        #pragma unroll
        for (int nt = 0; nt < 4; ++nt) {
            int hcol = h0w + nt * 16 + n;
            short8v b = *(const short8v*)(W3t + (size_t)hcol * 512 + koff);
            acc[nt] = __builtin_amdgcn_mfma_f32_16x16x32_bf16(a, b, acc[nt], 0, 0, 0);
        }
    }

    // epilogue: C/D col=lane&15 -> hcol, row=quad*4+reg -> tile j-row
    #pragma unroll
    for (int nt = 0; nt < 4; ++nt) {
        int hcol = h0w + nt * 16 + n;
        float aval = Abuf[(size_t)i * HDIM + hcol];
        float w40 = W4[hcol], w41 = W4[HDIM + hcol], w42 = W4[2*HDIM + hcol], w43 = W4[3*HDIM + hcol];
        float s = 0.f;
        #pragma unroll
        for (int reg = 0; reg < 4; ++reg) {
            int jj = jrow[quad * 4 + reg];
            if (jj >= 0) {
                float s0 = aval + Bbuf[(size_t)jj * HDIM + hcol] + acc[nt][reg];
                const float* lgp = elog + ((size_t)i * M_NODES + jj) * 4;
                float lg;
                lg = lgp[0]; if (lg > 0.f) s += fmaxf(s0 + lg * w40, 0.f);
                lg = lgp[1]; if (lg > 0.f) s += fmaxf(s0 + lg * w41, 0.f);
                lg = lgp[2]; if (lg > 0.f) s += fmaxf(s0 + lg * w42, 0.f);
                lg = lgp[3]; if (lg > 0.f) s += fmaxf(s0 + lg * w43, 0.f);
            }
        }
        s += __shfl_xor(s, 16);
        s += __shfl_xor(s, 32);
        if (lane < 16) atomicAdd(&child_next[(size_t)i * HDIM + hcol], s);
    }
}

extern "C" void kernel_launch(void* const* d_in, const int* in_sizes, int n_in,
                              void* d_out, int out_size, void* d_ws, size_t ws_size,
                              hipStream_t stream) {
    const float* parent   = (const float*)d_in[0];
    const float* W_parent = (const float*)d_in[1];
    const float* b_parent = (const float*)d_in[2];
    const float* W_exists = (const float*)d_in[3];
    const float* b_exists = (const float*)d_in[4];
    const float* W_el     = (const float*)d_in[5];
    const float* b_el     = (const float*)d_in[6];
    const float* W_ee     = (const float*)d_in[7];
    const float* b_ee     = (const float*)d_in[8];
    const float* W_ne     = (const float*)d_in[9];
    const float* b_ne     = (const float*)d_in[10];
    const float* W_child  = (const float*)d_in[11];
    const float* b_child  = (const float*)d_in[12];
    const float* W_sem    = (const float*)d_in[13];
    const float* b_sem    = (const float*)d_in[14];
    const float* W_child2 = (const float*)d_in[15];
    const float* b_child2 = (const float*)d_in[16];
    float* out = (float*)d_out;

    float* ws = (float*)d_ws;
    float* child_bufs = ws;                       // 3 * MH
    float* Xi       = ws + 3 * MH;                // MH each
    float* Xj       = Xi + MH;
    float* Abuf     = Xj + MH;
    float* Bbuf     = Abuf + MH;
    int*   node_ok  = (int*)(Bbuf + MH);          // 100
    int*   flag     = node_ok + M_NODES;          // 1
    int*   jcount   = flag + 1;                   // 100 (contiguous with flag)
    int*   jlist    = jcount + 100;               // 100*112 = 11200
    float* scratch  = (float*)(jlist + 11200 + 3);   // 8*MH f32, 16B-aligned
    short* W3t      = (short*)(scratch + 8 * MH);    // 2*512*512 bf16 = 1 MB
    float* hbuf     = Xi;                          // alias (Xi dead after msg it1)

    // outputs written in place:
    float* out_child  = out;                      // 51200
    float* out_sem    = out + 51200;              // 5700
    float* out_exists = out + 56900;              // 100
    float* out_elog   = out + 57000;              // 40000

    // 1. w3prep + child partials + zero flag/jcount + zero child1/child2
    front_kernel<<<1012, 256, 0, stream>>>(W_ne, W3t, parent, W_parent, scratch, flag,
                                           child_bufs + MH);

    // 2. child fold + exists/node_ok + quad GEMM -> Xi,Xj,Abuf,Bbuf (800 blocks)
    quad_ex<<<dim3(32, 25), 256, 0, stream>>>(scratch, b_parent, W_exists, b_exists,
        W_el, W_el + 512 * 512, W_ne, W_ne + 512 * 512, b_el, b_ne,
        child_bufs, out_exists, node_ok, Xi, Xj, Abuf, Bbuf);

    // 3. edge logits -> out, compaction (625 blocks, 4 pairs/wave)
    elog_kernel<<<625, 256, 0, stream>>>(Xi, Xj, W_ee, b_ee, node_ok, out_elog, flag,
                                         jcount, jlist);

    // 4. message it=0 -> child1 (h-split x2, atomic accumulate into pre-zeroed buffer)
    msgmfma<<<dim3(14, M_NODES), 256, 0, stream>>>(Xi, Xj, Abuf, Bbuf,
        W3t, W_ne + 1536 * 512, out_elog, jcount, jlist, child_bufs + MH);

    // 5. recompute A/B for it=1 from child1 (flag-select fallback to child0) (400 blocks)
    dual_ab<<<dim3(16, 25), 256, 0, stream>>>(flag, child_bufs, child_bufs + MH,
        W_ne + WNE_IT, W_ne + WNE_IT + 512 * 512, b_ne + 512, Abuf, Bbuf);

    // 6. message it=1 -> child2
    msgmfma<<<dim3(14, M_NODES), 256, 0, stream>>>(Xi, Xj, Abuf, Bbuf,
        W3t + 262144, W_ne + WNE_IT + 1536 * 512, out_elog, jcount, jlist,
        child_bufs + 2 * MH);

    // 7. h = relu(hcat @ W_child + b_child) (200 blocks)
    perm1536<<<dim3(8, 25), 256, 0, stream>>>(flag, child_bufs, W_child, b_child, hbuf);

    // 8. child_out + sem -> out directly (300 blocks)
    dual_rag<<<dim3(12, 25), 256, 0, stream>>>(hbuf, W_child2, b_child2, out_child,
                                               W_sem, b_sem, out_sem);
}

// Round 8
// 312.891 us; speedup vs baseline: 1.1524x; 1.1524x over previous
//
#include <hip/hip_runtime.h>

#define M_NODES 100
#define HDIM 512
#define MH (M_NODES*HDIM)       // 51200
#define WNE_IT (1540*512)

typedef __attribute__((ext_vector_type(8))) short short8v;   // 8 bf16 (4 VGPRs)
typedef __attribute__((ext_vector_type(4))) float float4v;   // MFMA acc

static __device__ __forceinline__ short f2b(float f) {
    union { float f; unsigned u; } v; v.f = f;
    unsigned r = (v.u + 0x7FFF + ((v.u >> 16) & 1)) >> 16;   // RNE
    return (short)r;
}

// ---- front: w3prep (0..511) + child split-K partials (512..911)
//      + zero child1/child2 (912..1011) + zero flag/jcount (block 0) ----
__global__ void front_kernel(const float* __restrict__ W_ne, short* __restrict__ W3t,
                             const float* __restrict__ parent, const float* __restrict__ Wp,
                             float* __restrict__ partial_c, int* __restrict__ flagjc,
                             float* __restrict__ child12) {
    __shared__ float sh[32 * 33];
    int bx = blockIdx.x, t = threadIdx.x;
    if (bx == 0 && t < 101) flagjc[t] = 0;          // flag + jcount[100]
    if (bx < 512) {
        int it = bx >> 8, rem = bx & 255, kt = rem & 15, ht = rem >> 4;
        const float* W3 = W_ne + (size_t)it * WNE_IT + 1024 * 512;
        int tx = t & 31, ty = t >> 5;               // ty 0..7
        #pragma unroll
        for (int r = 0; r < 4; ++r) {
            int k = kt * 32 + ty * 4 + r;
            sh[(ty * 4 + r) * 33 + tx] = W3[(size_t)k * 512 + ht * 32 + tx];
        }
        __syncthreads();
        #pragma unroll
        for (int r = 0; r < 4; ++r) {
            int h = ht * 32 + ty * 4 + r;
            W3t[(size_t)it * 262144 + (size_t)h * 512 + kt * 32 + tx] = f2b(sh[tx * 33 + ty * 4 + r]);
        }
    } else if (bx < 912) {
        int b = bx - 512;
        int bxx = b % 50, byy = b / 50;
        float* p = sh;                               // 64 floats
        int kc = byy * 64;
        if (t < 64) p[t] = parent[kc + t];
        __syncthreads();
        int o4 = (bxx * 256 + t) * 4;
        float4 acc = make_float4(0.f, 0.f, 0.f, 0.f);
        #pragma unroll 4
        for (int k = 0; k < 64; ++k) {
            float4 w = *(const float4*)(Wp + (size_t)(kc + k) * MH + o4);
            float pv = p[k];
            acc.x += pv * w.x; acc.y += pv * w.y; acc.z += pv * w.z; acc.w += pv * w.w;
        }
        *(float4*)(partial_c + (size_t)byy * MH + o4) = acc;
    } else {
        int id = (bx - 912) * 256 + t;               // 25600 float4 = 2*MH floats
        *(float4*)(child12 + (size_t)id * 4) = make_float4(0.f, 0.f, 0.f, 0.f);
    }
}

// tree-reduce helper over the 16 K-chunks: red[4][256], index = kq*16+g
static __device__ __forceinline__ void ks16_tree(float4 (*red)[256], int t) {
    #pragma unroll
    for (int st = 128; st >= 16; st >>= 1) {
        if (t < st) {
            #pragma unroll
            for (int r = 0; r < 4; ++r) {
                float4 a = red[r][t], b = red[r][t + st];
                a.x += b.x; a.y += b.y; a.z += b.z; a.w += b.w;
                red[r][t] = a;
            }
        }
        __syncthreads();
    }
}

// ---- quad GEMM, K-split-16 in block: grid (32,25). Fused child-fold + exists. ----
__global__ __launch_bounds__(256) void
quad_ex(const float* __restrict__ partial_c, const float* __restrict__ bp,
        const float* __restrict__ Wex, const float* __restrict__ bex,
        const float* __restrict__ B0, const float* __restrict__ B1,
        const float* __restrict__ B2, const float* __restrict__ B3,
        const float* __restrict__ bias0, const float* __restrict__ bias2,
        float* __restrict__ child0, float* __restrict__ exists_out, int* __restrict__ node_ok,
        float* __restrict__ O0, float* __restrict__ O1,
        float* __restrict__ O2, float* __restrict__ O3) {
    __shared__ float As[4][512];
    __shared__ float4 red[4][256];
    int t = threadIdx.x, bx = blockIdx.x, m0 = blockIdx.y * 4;
    // fold 8 partials + bias + relu -> As (child0 / exists from bx==0 blocks only)
    // NOTE: b_parent is the FULL [M*H]=51200 bias — index with the flat gcol.
    #pragma unroll
    for (int q2 = 0; q2 < 2; ++q2) {
        int slot = t + q2 * 256;
        int row = slot >> 7, c4 = (slot & 127) * 4;
        int gcol = (m0 + row) * 512 + c4;
        float4 s = *(const float4*)(bp + gcol);
        #pragma unroll
        for (int q = 0; q < 8; ++q) {
            float4 v = *(const float4*)(partial_c + (size_t)q * MH + gcol);
            s.x += v.x; s.y += v.y; s.z += v.z; s.w += v.w;
        }
        s.x = fmaxf(s.x, 0.f); s.y = fmaxf(s.y, 0.f);
        s.z = fmaxf(s.z, 0.f); s.w = fmaxf(s.w, 0.f);
        *(float4*)&As[row][c4] = s;
        if (bx == 0) *(float4*)(child0 + gcol) = s;
    }
    __syncthreads();
    if (bx == 0) {                                 // exists logits + node_ok
        int r = t >> 6, l = t & 63;
        const float* a = &As[r][l * 8];
        const float* w = Wex + l * 8;
        float s = a[0]*w[0] + a[1]*w[1] + a[2]*w[2] + a[3]*w[3]
                + a[4]*w[4] + a[5]*w[5] + a[6]*w[6] + a[7]*w[7];
        #pragma unroll
        for (int off = 32; off; off >>= 1) s += __shfl_down(s, off);
        if (l == 0) {
            float v = s + bex[0];
            exists_out[m0 + r] = v;
            node_ok[m0 + r] = (v > 0.f) ? 1 : 0;
        }
    }
    // K-split-16: thread (kq=t>>4, g=t&15); block covers 16 col4-groups
    int kq = t >> 4, g = t & 15;
    int col4 = bx * 16 + g, which = col4 >> 7, nn4 = col4 & 127;
    const float* B = (which == 0) ? B0 : (which == 1) ? B1 : (which == 2) ? B2 : B3;
    const float* bpB = B + nn4 * 4;
    float4 a0 = {0,0,0,0}, a1 = {0,0,0,0}, a2 = {0,0,0,0}, a3 = {0,0,0,0};
    int k0 = kq * 32;
    #pragma unroll 8
    for (int i = 0; i < 32; ++i) {
        int kk = k0 + i;
        float4 b = *(const float4*)(bpB + (size_t)kk * 512);
        float x0 = As[0][kk], x1 = As[1][kk], x2 = As[2][kk], x3 = As[3][kk];
        a0.x += x0*b.x; a0.y += x0*b.y; a0.z += x0*b.z; a0.w += x0*b.w;
        a1.x += x1*b.x; a1.y += x1*b.y; a1.z += x1*b.z; a1.w += x1*b.w;
        a2.x += x2*b.x; a2.y += x2*b.y; a2.z += x2*b.z; a2.w += x2*b.w;
        a3.x += x3*b.x; a3.y += x3*b.y; a3.z += x3*b.z; a3.w += x3*b.w;
    }
    red[0][t] = a0; red[1][t] = a1; red[2][t] = a2; red[3][t] = a3;
    __syncthreads();
    ks16_tree(red, t);
    if (t < 64) {
        int r2 = t >> 4, g2 = t & 15;
        int col4b = bx * 16 + g2, which2 = col4b >> 7, nn4b = col4b & 127;
        float4 s = red[r2][g2];
        if (which2 == 0) {
            float4 bb = *(const float4*)(bias0 + nn4b * 4);
            s.x += bb.x; s.y += bb.y; s.z += bb.z; s.w += bb.w;
        } else if (which2 == 2) {
            float4 bb = *(const float4*)(bias2 + nn4b * 4);
            s.x += bb.x; s.y += bb.y; s.z += bb.z; s.w += bb.w;
        }
        float* O = (which2 == 0) ? O0 : (which2 == 1) ? O1 : (which2 == 2) ? O2 : O3;
        *(float4*)(O + (size_t)(m0 + r2) * 512 + nn4b * 4) = s;
    }
}

// ---- it=1 A/B recompute, K-split-16: grid (16,25). A = flag ? child1 : child0 ----
__global__ __launch_bounds__(256) void
dual_ab(const int* __restrict__ flagp, const float* __restrict__ A0, const float* __restrict__ A1,
        const float* __restrict__ B0, const float* __restrict__ B1,
        const float* __restrict__ bias0, float* __restrict__ O0, float* __restrict__ O1) {
    __shared__ float As[4][512];
    __shared__ float4 red[4][256];
    int t = threadIdx.x, bx = blockIdx.x, m0 = blockIdx.y * 4;
    const float* A = (*flagp) ? A1 : A0;
    #pragma unroll
    for (int q2 = 0; q2 < 2; ++q2) {
        int slot = t + q2 * 256;
        int row = slot >> 7, c4 = (slot & 127) * 4;
        *(float4*)&As[row][c4] = *(const float4*)(A + (size_t)(m0 + row) * 512 + c4);
    }
    __syncthreads();
    int kq = t >> 4, g = t & 15;
    int col4 = bx * 16 + g;
    bool second = col4 >= 128;
    const float* B = second ? B1 : B0;
    int nn4 = col4 & 127;
    const float* bpB = B + nn4 * 4;
    float4 a0 = {0,0,0,0}, a1 = {0,0,0,0}, a2 = {0,0,0,0}, a3 = {0,0,0,0};
    int k0 = kq * 32;
    #pragma unroll 8
    for (int i = 0; i < 32; ++i) {
        int kk = k0 + i;
        float4 b = *(const float4*)(bpB + (size_t)kk * 512);
        float x0 = As[0][kk], x1 = As[1][kk], x2 = As[2][kk], x3 = As[3][kk];
        a0.x += x0*b.x; a0.y += x0*b.y; a0.z += x0*b.z; a0.w += x0*b.w;
        a1.x += x1*b.x; a1.y += x1*b.y; a1.z += x1*b.z; a1.w += x1*b.w;
        a2.x += x2*b.x; a2.y += x2*b.y; a2.z += x2*b.z; a2.w += x2*b.w;
        a3.x += x3*b.x; a3.y += x3*b.y; a3.z += x3*b.z; a3.w += x3*b.w;
    }
    red[0][t] = a0; red[1][t] = a1; red[2][t] = a2; red[3][t] = a3;
    __syncthreads();
    ks16_tree(red, t);
    if (t < 64) {
        int r2 = t >> 4, g2 = t & 15;
        int col4b = bx * 16 + g2;
        bool sec2 = col4b >= 128;
        int nn4b = col4b & 127;
        float4 s = red[r2][g2];
        if (!sec2) {
            float4 bb = *(const float4*)(bias0 + nn4b * 4);
            s.x += bb.x; s.y += bb.y; s.z += bb.z; s.w += bb.w;
        }
        float* O = sec2 ? O1 : O0;
        *(float4*)(O + (size_t)(m0 + r2) * 512 + nn4b * 4) = s;
    }
}

// ---- hcat GEMM [100,1536]xW_child, K-split-16: grid (8,25) ----
__global__ __launch_bounds__(256) void
perm1536(const int* __restrict__ flagp, const float* __restrict__ cb,
         const float* __restrict__ B, const float* __restrict__ bias, float* __restrict__ O) {
    __shared__ float As[4][1536];
    __shared__ float4 red[4][256];
    int t = threadIdx.x, bx = blockIdx.x, m0 = blockIdx.y * 4;
    int flag = *flagp;
    #pragma unroll
    for (int q2 = 0; q2 < 6; ++q2) {
        int slot = t + q2 * 256;                  // 1536 float4 slots: 4 rows x 384
        int row = slot / 384;
        int c4 = (slot - row * 384) * 4;
        int seg = c4 >> 9, off = c4 & 511;
        int se = flag ? seg : 0;                  // no-edge fallback: all segments = child0
        *(float4*)&As[row][c4] = *(const float4*)(cb + (size_t)se * MH + (size_t)(m0 + row) * 512 + off);
    }
    __syncthreads();
    int kq = t >> 4, g = t & 15;
    int nn4 = bx * 16 + g;                        // 0..127 (N=512)
    const float* bpB = B + nn4 * 4;
    float4 a0 = {0,0,0,0}, a1 = {0,0,0,0}, a2 = {0,0,0,0}, a3 = {0,0,0,0};
    int k0 = kq * 96;
    #pragma unroll 8
    for (int i = 0; i < 96; ++i) {
        int kk = k0 + i;
        float4 b = *(const float4*)(bpB + (size_t)kk * 512);
        float x0 = As[0][kk], x1 = As[1][kk], x2 = As[2][kk], x3 = As[3][kk];
        a0.x += x0*b.x; a0.y += x0*b.y; a0.z += x0*b.z; a0.w += x0*b.w;
        a1.x += x1*b.x; a1.y += x1*b.y; a1.z += x1*b.z; a1.w += x1*b.w;
        a2.x += x2*b.x; a2.y += x2*b.y; a2.z += x2*b.z; a2.w += x2*b.w;
        a3.x += x3*b.x; a3.y += x3*b.y; a3.z += x3*b.z; a3.w += x3*b.w;
    }
    red[0][t] = a0; red[1][t] = a1; red[2][t] = a2; red[3][t] = a3;
    __syncthreads();
    ks16_tree(red, t);
    if (t < 64) {
        int r2 = t >> 4, g2 = t & 15;
        int nn4b = bx * 16 + g2;
        float4 s = red[r2][g2];
        float4 bb = *(const float4*)(bias + nn4b * 4);
        s.x = fmaxf(s.x + bb.x, 0.f); s.y = fmaxf(s.y + bb.y, 0.f);
        s.z = fmaxf(s.z + bb.z, 0.f); s.w = fmaxf(s.w + bb.w, 0.f);
        *(float4*)(O + (size_t)(m0 + r2) * 512 + nn4b * 4) = s;
    }
}

// ---- final dual, K-split-16: grid (12,25). bx<8: W_child2 (relu); bx>=8: W_sem ragged ----
__global__ __launch_bounds__(256) void
dual_rag(const float* __restrict__ A,
         const float* __restrict__ B0, const float* __restrict__ bias0, float* __restrict__ O0,
         const float* __restrict__ B2, const float* __restrict__ bias2, float* __restrict__ O2) {
    __shared__ float As[4][512];
    __shared__ float4 red[4][256];
    int t = threadIdx.x, bx = blockIdx.x, m0 = blockIdx.y * 4;
    #pragma unroll
    for (int q2 = 0; q2 < 2; ++q2) {
        int slot = t + q2 * 256;
        int row = slot >> 7, c4 = (slot & 127) * 4;
        *(float4*)&As[row][c4] = *(const float4*)(A + (size_t)(m0 + row) * 512 + c4);
    }
    __syncthreads();
    int kq = t >> 4, g = t & 15;
    float4 a0 = {0,0,0,0}, a1 = {0,0,0,0}, a2 = {0,0,0,0}, a3 = {0,0,0,0};
    int k0 = kq * 32;
    if (bx < 8) {
        int nn4 = bx * 16 + g;
        const float* bpB = B0 + nn4 * 4;
        #pragma unroll 8
        for (int i = 0; i < 32; ++i) {
            int kk = k0 + i;
            float4 b = *(const float4*)(bpB + (size_t)kk * 512);
            float x0 = As[0][kk], x1 = As[1][kk], x2 = As[2][kk], x3 = As[3][kk];
            a0.x += x0*b.x; a0.y += x0*b.y; a0.z += x0*b.z; a0.w += x0*b.w;
            a1.x += x1*b.x; a1.y += x1*b.y; a1.z += x1*b.z; a1.w += x1*b.w;
            a2.x += x2*b.x; a2.y += x2*b.y; a2.z += x2*b.z; a2.w += x2*b.w;
            a3.x += x3*b.x; a3.y += x3*b.y; a3.z += x3*b.z; a3.w += x3*b.w;
        }
    } else {
        int col = (bx - 8) * 16 + g;              // 0..63 covers 57
        if (col < 57) {
            #pragma unroll 8
            for (int i = 0; i < 32; ++i) {
                int kk = k0 + i;
                float b = B2[(size_t)kk * 57 + col];
                a0.x += As[0][kk] * b; a1.x += As[1][kk] * b;
                a2.x += As[2][kk] * b; a3.x += As[3][kk] * b;
            }
        }
    }
    red[0][t] = a0; red[1][t] = a1; red[2][t] = a2; red[3][t] = a3;
    __syncthreads();
    ks16_tree(red, t);
    if (t < 64) {
        int r2 = t >> 4, g2 = t & 15;
        float4 s = red[r2][g2];
        if (bx < 8) {
            int nn4b = bx * 16 + g2;
            float4 bb = *(const float4*)(bias0 + nn4b * 4);
            s.x = fmaxf(s.x + bb.x, 0.f); s.y = fmaxf(s.y + bb.y, 0.f);
            s.z = fmaxf(s.z + bb.z, 0.f); s.w = fmaxf(s.w + bb.w, 0.f);
            *(float4*)(O0 + (size_t)(m0 + r2) * 512 + nn4b * 4) = s;
        } else {
            int col = (bx - 8) * 16 + g2;
            if (col < 57) O2[(size_t)(m0 + r2) * 57 + col] = s.x + bias2[col];
        }
    }
}

// elog (-> out): one wave per (i,j) pair; NO atomics, NO volatile — writes anyb[pair].
__global__ void elog_kernel(const float* __restrict__ Xi, const float* __restrict__ Xj,
                            const float* __restrict__ Wee, const float* __restrict__ bee,
                            const int* __restrict__ node_ok,
                            float* __restrict__ elog, int* __restrict__ anyb) {
    int wid = threadIdx.x >> 6, lane = threadIdx.x & 63;
    int pair = blockIdx.x * 4 + wid;
    int i = pair / M_NODES, j = pair - (pair / M_NODES) * M_NODES;
    int k0 = lane * 8;
    float4 xa = *(const float4*)(Xi + (size_t)i * HDIM + k0);
    float4 xb = *(const float4*)(Xi + (size_t)i * HDIM + k0 + 4);
    float4 ya = *(const float4*)(Xj + (size_t)j * HDIM + k0);
    float4 yb = *(const float4*)(Xj + (size_t)j * HDIM + k0 + 4);
    float e0 = fmaxf(xa.x + ya.x, 0.f), e1 = fmaxf(xa.y + ya.y, 0.f);
    float e2 = fmaxf(xa.z + ya.z, 0.f), e3 = fmaxf(xa.w + ya.w, 0.f);
    float e4 = fmaxf(xb.x + yb.x, 0.f), e5 = fmaxf(xb.y + yb.y, 0.f);
    float e6 = fmaxf(xb.z + yb.z, 0.f), e7 = fmaxf(xb.w + yb.w, 0.f);
    float s[4];
    #pragma unroll
    for (int tt = 0; tt < 4; ++tt) {
        float4 wa = *(const float4*)(Wee + tt * HDIM + k0);
        float4 wb = *(const float4*)(Wee + tt * HDIM + k0 + 4);
        s[tt] = e0*wa.x + e1*wa.y + e2*wa.z + e3*wa.w + e4*wb.x + e5*wb.y + e6*wb.z + e7*wb.w;
    }
    #pragma unroll
    for (int off = 32; off; off >>= 1) {
        s[0] += __shfl_down(s[0], off); s[1] += __shfl_down(s[1], off);
        s[2] += __shfl_down(s[2], off); s[3] += __shfl_down(s[3], off);
    }
    if (lane == 0) {
        bool ok = node_ok[i] && node_ok[j];
        float lg0 = s[0] + bee[0], lg1 = s[1] + bee[1], lg2 = s[2] + bee[2], lg3 = s[3] + bee[3];
        elog[pair * 4 + 0] = lg0; elog[pair * 4 + 1] = lg1;
        elog[pair * 4 + 2] = lg2; elog[pair * 4 + 3] = lg3;
        anyb[pair] = (ok && (lg0 > 0.f || lg1 > 0.f || lg2 > 0.f || lg3 > 0.f)) ? 1 : 0;
    }
}

// ballot-compaction: one wave per i (grid 25 x 256 thr = 100 waves). <=100 atomics total.
__global__ void compact_kernel(const int* __restrict__ anyb, int* __restrict__ jcount,
                               int* __restrict__ jlist, int* __restrict__ flag) {
    int wid = threadIdx.x >> 6, lane = threadIdx.x & 63;
    int i = blockIdx.x * 4 + wid;
    const int* ab = anyb + i * M_NODES;
    bool b0 = ab[lane] != 0;                         // j = lane (0..63)
    bool b1 = (lane < 36) ? (ab[64 + lane] != 0) : false;  // j = 64+lane (64..99)
    unsigned long long m0 = __ballot(b0);
    unsigned long long m1 = __ballot(b1);
    int c0 = __popcll(m0);
    int cnt = c0 + __popcll(m1);
    unsigned long long below = (lane == 0) ? 0ull : (~0ull >> (64 - lane));
    if (b0) jlist[i * 112 + __popcll(m0 & below)] = lane;
    if (b1) jlist[i * 112 + c0 + __popcll(m1 & below)] = 64 + lane;
    if (lane == 0) {
        jcount[i] = cnt;
        if (cnt > 0) atomicOr(flag, 1);
    }
}

// ---- MFMA message step, h-split: block (jt, hs, i) covers 256 h-cols, 256 thr. ----
__global__ __launch_bounds__(256) void
msgmfma(const float* __restrict__ Xi, const float* __restrict__ Xj,
        const float* __restrict__ Abuf, const float* __restrict__ Bbuf,
        const short* __restrict__ W3t, const float* __restrict__ W4,
        const float* __restrict__ elog, const int* __restrict__ jcount,
        const int* __restrict__ jlist, float* __restrict__ child_next) {
    __shared__ short ELb[16][520];             // bf16, +8 pad
    __shared__ int jrow[16];
    int i = blockIdx.y;
    int jt = blockIdx.x >> 1, hs = blockIdx.x & 1;
    int jcnt = jcount[i];
    int j0 = jt * 16;
    if (j0 >= jcnt) return;                    // sparse early-exit (child_next pre-zeroed)
    int t = threadIdx.x;
    int wave = t >> 6, lane = t & 63;

    if (t < 16) jrow[t] = (j0 + t < jcnt) ? jlist[i * 112 + j0 + t] : -1;
    __syncthreads();
    int k0 = (t & 127) * 4;
    int r0 = t >> 7;                           // 0..1
    float4 xi = *(const float4*)(Xi + (size_t)i * HDIM + k0);
    #pragma unroll
    for (int s = 0; s < 8; ++s) {
        int row = r0 + s * 2;                  // covers 16 rows
        int j = jrow[row];
        short4 b;
        if (j >= 0) {
            float4 xj = *(const float4*)(Xj + (size_t)j * HDIM + k0);
            b.x = f2b(fmaxf(xi.x + xj.x, 0.f));
            b.y = f2b(fmaxf(xi.y + xj.y, 0.f));
            b.z = f2b(fmaxf(xi.z + xj.z, 0.f));
            b.w = f2b(fmaxf(xi.w + xj.w, 0.f));
        } else {
            b.x = b.y = b.z = b.w = 0;
        }
        *(short4*)&ELb[row][k0] = b;
    }
    __syncthreads();

    int n = lane & 15, quad = lane >> 4;
    int h0w = hs * 256 + wave * 64;            // 4 waves x 64 cols = 256-col slice
    float4v acc[4];
    #pragma unroll
    for (int nt = 0; nt < 4; ++nt) acc[nt] = (float4v){0.f, 0.f, 0.f, 0.f};

    for (int kc = 0; kc < 16; ++kc) {
        int koff = kc * 32 + quad * 8;
        short8v a = *(const short8v*)&ELb[n][koff];
        #pragma unroll
        for (int nt = 0; nt < 4; ++nt) {
            int hcol = h0w + nt * 16 + n;
            short8v b = *(const short8v*)(W3t + (size_t)hcol * 512 + koff);
            acc[nt] = __builtin_amdgcn_mfma_f32_16x16x32_bf16(a, b, acc[nt], 0, 0, 0);
        }
    }

    // epilogue: C/D col=lane&15 -> hcol, row=quad*4+reg -> tile j-row
    #pragma unroll
    for (int nt = 0; nt < 4; ++nt) {
        int hcol = h0w + nt * 16 + n;
        float aval = Abuf[(size_t)i * HDIM + hcol];
        float w40 = W4[hcol], w41 = W4[HDIM + hcol], w42 = W4[2*HDIM + hcol], w43 = W4[3*HDIM + hcol];
        float s = 0.f;
        #pragma unroll
        for (int reg = 0; reg < 4; ++reg) {
            int jj = jrow[quad * 4 + reg];
            if (jj >= 0) {
                float s0 = aval + Bbuf[(size_t)jj * HDIM + hcol] + acc[nt][reg];
                const float* lgp = elog + ((size_t)i * M_NODES + jj) * 4;
                float lg;
                lg = lgp[0]; if (lg > 0.f) s += fmaxf(s0 + lg * w40, 0.f);
                lg = lgp[1]; if (lg > 0.f) s += fmaxf(s0 + lg * w41, 0.f);
                lg = lgp[2]; if (lg > 0.f) s += fmaxf(s0 + lg * w42, 0.f);
                lg = lgp[3]; if (lg > 0.f) s += fmaxf(s0 + lg * w43, 0.f);
            }
        }
        s += __shfl_xor(s, 16);
        s += __shfl_xor(s, 32);
        if (lane < 16) atomicAdd(&child_next[(size_t)i * HDIM + hcol], s);
    }
}

extern "C" void kernel_launch(void* const* d_in, const int* in_sizes, int n_in,
                              void* d_out, int out_size, void* d_ws, size_t ws_size,
                              hipStream_t stream) {
    const float* parent   = (const float*)d_in[0];
    const float* W_parent = (const float*)d_in[1];
    const float* b_parent = (const float*)d_in[2];
    const float* W_exists = (const float*)d_in[3];
    const float* b_exists = (const float*)d_in[4];
    const float* W_el     = (const float*)d_in[5];
    const float* b_el     = (const float*)d_in[6];
    const float* W_ee     = (const float*)d_in[7];
    const float* b_ee     = (const float*)d_in[8];
    const float* W_ne     = (const float*)d_in[9];
    const float* b_ne     = (const float*)d_in[10];
    const float* W_child  = (const float*)d_in[11];
    const float* b_child  = (const float*)d_in[12];
    const float* W_sem    = (const float*)d_in[13];
    const float* b_sem    = (const float*)d_in[14];
    const float* W_child2 = (const float*)d_in[15];
    const float* b_child2 = (const float*)d_in[16];
    float* out = (float*)d_out;

    float* ws = (float*)d_ws;
    float* child_bufs = ws;                       // 3 * MH
    float* Xi       = ws + 3 * MH;                // MH each
    float* Xj       = Xi + MH;
    float* Abuf     = Xj + MH;
    float* Bbuf     = Abuf + MH;
    int*   node_ok  = (int*)(Bbuf + MH);          // 100
    int*   flag     = node_ok + M_NODES;          // 1
    int*   jcount   = flag + 1;                   // 100 (contiguous with flag)
    int*   jlist    = jcount + 100;               // 100*112 = 11200
    int*   anyb     = jlist + 11200;              // 10000
    float* scratch  = (float*)(anyb + 10000 + 7); // 8*MH f32, 16B-aligned (offset 379808)
    short* W3t      = (short*)(scratch + 8 * MH); // 2*512*512 bf16 = 1 MB
    float* hbuf     = Xi;                          // alias (Xi dead after msg it1)

    // outputs written in place:
    float* out_child  = out;                      // 51200
    float* out_sem    = out + 51200;              // 5700
    float* out_exists = out + 56900;              // 100
    float* out_elog   = out + 57000;              // 40000

    // 1. w3prep + child partials + zero flag/jcount + zero child1/child2
    front_kernel<<<1012, 256, 0, stream>>>(W_ne, W3t, parent, W_parent, scratch, flag,
                                           child_bufs + MH);

    // 2. child fold + exists/node_ok + quad GEMM -> Xi,Xj,Abuf,Bbuf (800 blocks)
    quad_ex<<<dim3(32, 25), 256, 0, stream>>>(scratch, b_parent, W_exists, b_exists,
        W_el, W_el + 512 * 512, W_ne, W_ne + 512 * 512, b_el, b_ne,
        child_bufs, out_exists, node_ok, Xi, Xj, Abuf, Bbuf);

    // 3. edge logits -> out + any-bytes (2500 blocks, atomic-free)
    elog_kernel<<<2500, 256, 0, stream>>>(Xi, Xj, W_ee, b_ee, node_ok, out_elog, anyb);

    // 3b. ballot-compaction -> jcount/jlist/flag (100 waves)
    compact_kernel<<<25, 256, 0, stream>>>(anyb, jcount, jlist, flag);

    // 4. message it=0 -> child1 (h-split x2, atomic accumulate into pre-zeroed buffer)
    msgmfma<<<dim3(14, M_NODES), 256, 0, stream>>>(Xi, Xj, Abuf, Bbuf,
        W3t, W_ne + 1536 * 512, out_elog, jcount, jlist, child_bufs + MH);

    // 5. recompute A/B for it=1 from child1 (flag-select fallback to child0) (400 blocks)
    dual_ab<<<dim3(16, 25), 256, 0, stream>>>(flag, child_bufs, child_bufs + MH,
        W_ne + WNE_IT, W_ne + WNE_IT + 512 * 512, b_ne + 512, Abuf, Bbuf);

    // 6. message it=1 -> child2
    msgmfma<<<dim3(14, M_NODES), 256, 0, stream>>>(Xi, Xj, Abuf, Bbuf,
        W3t + 262144, W_ne + WNE_IT + 1536 * 512, out_elog, jcount, jlist,
        child_bufs + 2 * MH);

    // 7. h = relu(hcat @ W_child + b_child) (200 blocks)
    perm1536<<<dim3(8, 25), 256, 0, stream>>>(flag, child_bufs, W_child, b_child, hbuf);

    // 8. child_out + sem -> out directly (300 blocks)
    dual_rag<<<dim3(12, 25), 256, 0, stream>>>(hbuf, W_child2, b_child2, out_child,
                                               W_sem, b_sem, out_sem);
}